// Round 16
// baseline (436.647 us; speedup 1.0000x reference)
//
#include <hip/hip_runtime.h>

#define DI __device__ __forceinline__

typedef __attribute__((ext_vector_type(8))) short short8;
typedef __attribute__((ext_vector_type(4))) float f32x4;

// ---- problem constants ----
#define DM   1024      // model dim
#define TT   2048      // total tokens (B*S)
#define SEQ  1024
#define NHD  16        // heads
#define HDD  64        // head dim
#define NE   8         // experts
#define FF   2816

DI ushort f2bf(float f){
  union { float f; unsigned u; } c; c.f = f;
  unsigned u = c.u;
  u += 0x7fffu + ((u >> 16) & 1u);
  return (ushort)(u >> 16);
}
DI float bf2f(ushort b){
  union { unsigned u; float f; } c; c.u = ((unsigned)b) << 16;
  return c.f;
}
DI unsigned pk2(float a, float b){ return (unsigned)f2bf(a) | ((unsigned)f2bf(b) << 16); }
DI uint2 mku2(unsigned a, unsigned b){ uint2 r; r.x = a; r.y = b; return r; }

DI f32x4 MFMA(short8 a, short8 b, f32x4 c){
  return __builtin_amdgcn_mfma_f32_16x16x32_bf16(a, b, c, 0, 0, 0);
}

// async global->LDS, 16B per lane; LDS dest is wave-uniform base + lane*16
DI void gload16(const void* g, void* l){
  __builtin_amdgcn_global_load_lds(
      (const __attribute__((address_space(1))) unsigned*)g,
      (__attribute__((address_space(3))) unsigned*)l, 16, 0, 0);
}

// swizzled LDS byte offset, rows of 128B, 8 chunks of 16B (proven zero-conflict)
#define LDSWZB(row, p) (((row) * 128) + ((((p) ^ ((row) & 7))) * 16))

// ============ 1. fused: RMSNorm(x) + attn-weight split ============
__global__ __launch_bounds__(256) void k_pre(
    const float* __restrict__ x, const float* __restrict__ anw,
    ushort* __restrict__ xh, ushort* __restrict__ xl,
    const float* __restrict__ wq, const float* __restrict__ wk,
    const float* __restrict__ wv, const float* __restrict__ wo,
    ushort* __restrict__ wqh, ushort* __restrict__ wql,
    ushort* __restrict__ wkh, ushort* __restrict__ wkl,
    ushort* __restrict__ wvh, ushort* __restrict__ wvl,
    ushort* __restrict__ woh, ushort* __restrict__ wol)
{
  int bid = blockIdx.x, tid = threadIdx.x;
  if (bid >= 2048) {                 // ---- wsplit ----
    int q = bid - 2048;
    int y = q >> 10;
    const float* W = y == 0 ? wq : (y == 1 ? wk : (y == 2 ? wv : wo));
    ushort* H = y == 0 ? wqh : (y == 1 ? wkh : (y == 2 ? wvh : woh));
    ushort* L = y == 0 ? wql : (y == 1 ? wkl : (y == 2 ? wvl : wol));
    int i = (q & 1023) * 256 + tid;
    float4 v = ((const float4*)W)[i];
    ushort h0 = f2bf(v.x), h1 = f2bf(v.y), h2 = f2bf(v.z), h3 = f2bf(v.w);
    ((uint2*)H)[i] = mku2((unsigned)h0 | ((unsigned)h1 << 16),
                          (unsigned)h2 | ((unsigned)h3 << 16));
    ((uint2*)L)[i] = mku2(pk2(v.x - bf2f(h0), v.y - bf2f(h1)),
                          pk2(v.z - bf2f(h2), v.w - bf2f(h3)));
    return;
  }
  // ---- rmsnorm ----
  int row = bid;
  float4 v = ((const float4*)(x + (size_t)row * DM))[tid];
  float ss = v.x*v.x + v.y*v.y + v.z*v.z + v.w*v.w;
#pragma unroll
  for (int m = 32; m >= 1; m >>= 1) ss += __shfl_xor(ss, m);
  __shared__ float sh[4];
  if ((tid & 63) == 0) sh[tid >> 6] = ss;
  __syncthreads();
  ss = sh[0] + sh[1] + sh[2] + sh[3];
  float rstd = 1.0f / sqrtf(ss * (1.0f / DM) + 1e-5f);
  float4 wv2 = ((const float4*)anw)[tid];
  float o0 = v.x * rstd * wv2.x, o1 = v.y * rstd * wv2.y;
  float o2 = v.z * rstd * wv2.z, o3 = v.w * rstd * wv2.w;
  ushort h0 = f2bf(o0), h1 = f2bf(o1), h2 = f2bf(o2), h3 = f2bf(o3);
  ((uint2*)(xh + (size_t)row * DM))[tid] =
      mku2((unsigned)h0 | ((unsigned)h1 << 16), (unsigned)h2 | ((unsigned)h3 << 16));
  ((uint2*)(xl + (size_t)row * DM))[tid] =
      mku2(pk2(o0 - bf2f(h0), o1 - bf2f(h1)), pk2(o2 - bf2f(h2), o3 - bf2f(h3)));
}

// ============ 1c. standalone cw13 (fallback) ============
__global__ __launch_bounds__(256) void k_cw13(const float* __restrict__ w1,
                                              const float* __restrict__ w3,
                                              ushort* __restrict__ w1b,
                                              ushort* __restrict__ w3b)
{
  const float* src = blockIdx.y ? w3 : w1;
  ushort* dst = blockIdx.y ? w3b : w1b;
  const size_t N4 = (size_t)NE * FF * DM / 4;
  for (size_t i = (size_t)blockIdx.x * 256 + threadIdx.x; i < N4;
       i += (size_t)gridDim.x * 256) {
    float4 v = ((const float4*)src)[i];
    ((uint2*)dst)[i] = mku2(pk2(v.x, v.y), pk2(v.z, v.w));
  }
}

// ============ 2. fused QKV GEMM + RoPE (pure, r13 geometry) ============
// BM=128, BN=128, BK=64, 4 waves (2x2), 64KB LDS, grid 384.
__global__ __launch_bounds__(256, 2) void k_gemm_qkv(
    const ushort* __restrict__ xh, const ushort* __restrict__ xl,
    const ushort* __restrict__ wqh, const ushort* __restrict__ wql,
    const ushort* __restrict__ wkh, const ushort* __restrict__ wkl,
    const ushort* __restrict__ wvh, const ushort* __restrict__ wvl,
    const float* __restrict__ fc, const float* __restrict__ fs,
    ushort* __restrict__ qh, ushort* __restrict__ ql,
    ushort* __restrict__ kh, ushort* __restrict__ kl,
    ushort* __restrict__ vh, ushort* __restrict__ vl)
{
  __shared__ __align__(16) char lds[65536];
  char* Ah = lds;          char* Al = lds + 16384;
  char* Bh = lds + 32768;  char* Bl = lds + 49152;
  int bid = blockIdx.x, tid = threadIdx.x;
  int bn = bid % 24, bm = bid / 24;
  int which = bn >> 3, bnn = bn & 7;
  const ushort* WH = which == 0 ? wqh : (which == 1 ? wkh : wvh);
  const ushort* WL = which == 0 ? wql : (which == 1 ? wkl : wvl);
  int lane = tid & 63, w = tid >> 6, wr = w >> 1, wc = w & 1;
  int r0 = lane >> 3, pp = lane & 7;
  size_t asrc[4], bsrc[4]; int cdst[4];
#pragma unroll
  for (int i = 0; i < 4; i++) {
    int c = w * 4 + i;
    int row = c * 8 + r0;
    asrc[i] = (size_t)(bm * 128 + row) * DM + (pp ^ r0) * 8;
    bsrc[i] = (size_t)(bnn * 128 + row) * DM + (pp ^ r0) * 8;
    cdst[i] = c * 1024;
  }
  f32x4 acc[4][4] = {};
  for (int kb = 0; kb < DM; kb += 64) {
    __syncthreads();
#pragma unroll
    for (int i = 0; i < 4; i++) {
      gload16(xh + asrc[i] + kb, Ah + cdst[i]);
      gload16(xl + asrc[i] + kb, Al + cdst[i]);
      gload16(WH + bsrc[i] + kb, Bh + cdst[i]);
      gload16(WL + bsrc[i] + kb, Bl + cdst[i]);
    }
    __syncthreads();
#pragma unroll
    for (int kk = 0; kk < 2; kk++) {
      int j = kk * 4 + (lane >> 4);
      short8 ar[4], al[4];
#pragma unroll
      for (int mi = 0; mi < 4; mi++) {
        int row = wr * 64 + mi * 16 + (lane & 15);
        ar[mi] = *(const short8*)(Ah + LDSWZB(row, j));
        al[mi] = *(const short8*)(Al + LDSWZB(row, j));
      }
#pragma unroll
      for (int ni = 0; ni < 4; ni++) {
        int n = wc * 64 + ni * 16 + (lane & 15);
        short8 b_h = *(const short8*)(Bh + LDSWZB(n, j));
        short8 b_l = *(const short8*)(Bl + LDSWZB(n, j));
#pragma unroll
        for (int mi = 0; mi < 4; mi++) {
          acc[mi][ni] = MFMA(ar[mi], b_h, acc[mi][ni]);
          acc[mi][ni] = MFMA(al[mi], b_h, acc[mi][ni]);
          acc[mi][ni] = MFMA(ar[mi], b_l, acc[mi][ni]);
        }
      }
    }
  }
  ushort* OH = which == 0 ? qh : kh;
  ushort* OL = which == 0 ? ql : kl;
#pragma unroll
  for (int mi = 0; mi < 4; mi++)
#pragma unroll
    for (int ni = 0; ni < 4; ni++)
#pragma unroll
      for (int r = 0; r < 4; r++) {
        int rg = bm*128 + wr*64 + mi*16 + (lane >> 4)*4 + r;
        int cg = bnn*128 + wc*64 + ni*16 + (lane & 15);
        float v = acc[mi][ni][r];
        int b = rg >> 10, s = rg & 1023, hh = cg >> 6, hd = cg & 63;
        if (which <= 1) {
          float p = __shfl_xor(v, 1);
          int pi = hd >> 1;
          float c = fc[s*32 + pi], sn = fs[s*32 + pi];
          float rr = (hd & 1) ? (p * sn + v * c) : (v * c - p * sn);
          size_t o = ((size_t)(b*NHD + hh) * SEQ + s) * HDD + hd;
          ushort hv = f2bf(rr);
          OH[o] = hv; OL[o] = f2bf(rr - bf2f(hv));
        } else {
          size_t o = ((size_t)((b*NHD + hh)*HDD + hd)) * SEQ + s;
          ushort hv = f2bf(v);
          vh[o] = hv; vl[o] = f2bf(v - bf2f(hv));
        }
      }
}

// ============ 4. fused: causal flash attention + cw13 co-blocks ============
__global__ __launch_bounds__(256) void k_attn_prep(
    const ushort* __restrict__ qh_, const ushort* __restrict__ ql_,
    const ushort* __restrict__ kh_, const ushort* __restrict__ kl_,
    const ushort* __restrict__ vh_, const ushort* __restrict__ vl_,
    ushort* __restrict__ oh_, ushort* __restrict__ ol_,
    const float* __restrict__ w1, const float* __restrict__ w3,
    ushort* __restrict__ w1b, ushort* __restrict__ w3b)
{
  __shared__ __align__(16) char smem[49152];
  int bid = blockIdx.x, tid = threadIdx.x;

  if (bid >= 512) {                     // ---- cw13 co-blocks ----
    int pid = bid - 512;
    const size_t N4 = (size_t)NE * FF * DM / 4;
    for (size_t i = (size_t)pid * 256 + tid; i < N4; i += (size_t)512 * 256) {
      float4 v = ((const float4*)w1)[i];
      ((uint2*)w1b)[i] = mku2(pk2(v.x, v.y), pk2(v.z, v.w));
      float4 u = ((const float4*)w3)[i];
      ((uint2*)w3b)[i] = mku2(pk2(u.x, u.y), pk2(u.z, u.w));
    }
    return;
  }

  char* Kh = smem;          char* Kl = smem + 8192;
  char* Vh = smem + 16384;  char* Vl = smem + 24576;
  ushort* Ph = (ushort*)(smem + 32768);
  ushort* Pl = (ushort*)(smem + 40960);
  int qt = bid & 15, bh = bid >> 4;
  int lane = tid & 63, w = tid >> 6;
  int r0 = lane >> 3, pp = lane & 7;
  short8 qfh[2], qfl[2];
  int qrow = qt*64 + w*16 + (lane & 15);
#pragma unroll
  for (int ks = 0; ks < 2; ks++) {
    size_t g = ((size_t)bh * SEQ + qrow) * HDD + ks*32 + (lane >> 4)*8;
    qfh[ks] = *(const short8*)(qh_ + g);
    qfl[ks] = *(const short8*)(ql_ + g);
  }
  size_t kbase[2], vbase[2];
#pragma unroll
  for (int i = 0; i < 2; i++) {
    int c = 2*w + i;
    kbase[i] = ((size_t)bh * SEQ + c*8 + r0) * 64 + (pp ^ r0) * 8;
    vbase[i] = ((size_t)bh * 64 + c*8 + r0) * SEQ + (pp ^ r0) * 8;
  }
  f32x4 oacc[4] = {};
  float mrun[4], lrun[4];
#pragma unroll
  for (int r = 0; r < 4; r++) { mrun[r] = -1e30f; lrun[r] = 0.0f; }

  for (int kt = 0; kt <= qt; kt++) {
    __syncthreads();
#pragma unroll
    for (int i = 0; i < 2; i++) {
      int c = 2*w + i;
      size_t ko = kbase[i] + (size_t)kt * 64 * 64;
      size_t vo = vbase[i] + (size_t)kt * 64;
      gload16(kh_ + ko, Kh + c*1024);
      gload16(kl_ + ko, Kl + c*1024);
      gload16(vh_ + vo, Vh + c*1024);
      gload16(vl_ + vo, Vl + c*1024);
    }
    __syncthreads();
    f32x4 sa[4] = {};
#pragma unroll
    for (int j2 = 0; j2 < 4; j2++) {
#pragma unroll
      for (int ks = 0; ks < 2; ks++) {
        int kr = j2*16 + (lane & 15);
        int j = ks*4 + (lane >> 4);
        short8 b_h = *(const short8*)(Kh + LDSWZB(kr, j));
        short8 b_l = *(const short8*)(Kl + LDSWZB(kr, j));
        sa[j2] = MFMA(qfh[ks], b_h, sa[j2]);
        sa[j2] = MFMA(qfl[ks], b_h, sa[j2]);
        sa[j2] = MFMA(qfh[ks], b_l, sa[j2]);
      }
    }
    float sv[4][4];
#pragma unroll
    for (int j2 = 0; j2 < 4; j2++)
#pragma unroll
      for (int r = 0; r < 4; r++) {
        float xx = sa[j2][r] * 0.125f;
        if (kt == qt) {
          int kv = j2*16 + (lane & 15), qi = w*16 + (lane >> 4)*4 + r;
          if (kv > qi) xx = -1e30f;
        }
        sv[j2][r] = xx;
      }
#pragma unroll
    for (int r = 0; r < 4; r++) {
      float mx = fmaxf(fmaxf(sv[0][r], sv[1][r]), fmaxf(sv[2][r], sv[3][r]));
#pragma unroll
      for (int m = 8; m >= 1; m >>= 1) mx = fmaxf(mx, __shfl_xor(mx, m));
      float mn = fmaxf(mrun[r], mx);
      float alp = __expf(mrun[r] - mn);
      mrun[r] = mn;
      float rs = 0.0f;
#pragma unroll
      for (int j2 = 0; j2 < 4; j2++) { float pv = __expf(sv[j2][r] - mn); sv[j2][r] = pv; rs += pv; }
#pragma unroll
      for (int m = 8; m >= 1; m >>= 1) rs += __shfl_xor(rs, m);
      lrun[r] = lrun[r] * alp + rs;
#pragma unroll
      for (int hf = 0; hf < 4; hf++) oacc[hf][r] *= alp;
    }
#pragma unroll
    for (int j2 = 0; j2 < 4; j2++)
#pragma unroll
      for (int r = 0; r < 4; r++) {
        int row = (lane >> 4)*4 + r, col = j2*16 + (lane & 15);
        int d = w*1024 + row*64 + (((col >> 3) ^ (row & 7)) * 8) + (col & 7);
        ushort hv = f2bf(sv[j2][r]);
        Ph[d] = hv; Pl[d] = f2bf(sv[j2][r] - bf2f(hv));
      }
#pragma unroll
    for (int hf = 0; hf < 4; hf++) {
#pragma unroll
      for (int ks = 0; ks < 2; ks++) {
        int prow = lane & 15;
        int j = ks*4 + (lane >> 4);
        int pg = (j ^ (prow & 7)) * 8;
        short8 pfh = *(const short8*)&Ph[w*1024 + prow*64 + pg];
        short8 pfl = *(const short8*)&Pl[w*1024 + prow*64 + pg];
        int vrow = hf*16 + (lane & 15);
        short8 vfh = *(const short8*)(Vh + LDSWZB(vrow, j));
        short8 vfl = *(const short8*)(Vl + LDSWZB(vrow, j));
        oacc[hf] = MFMA(pfh, vfh, oacc[hf]);
        oacc[hf] = MFMA(pfl, vfh, oacc[hf]);
        oacc[hf] = MFMA(pfh, vfl, oacc[hf]);
      }
    }
  }
  int b = bh >> 4, h = bh & 15;
#pragma unroll
  for (int r = 0; r < 4; r++) {
    float li = 1.0f / lrun[r];
    int srow = qt*64 + w*16 + (lane >> 4)*4 + r;
#pragma unroll
    for (int hf = 0; hf < 4; hf++) {
      float v = oacc[hf][r] * li;
      size_t o = ((size_t)(b*SEQ + srow)) * DM + h*HDD + hf*16 + (lane & 15);
      ushort hv = f2bf(v);
      oh_[o] = hv; ol_[o] = f2bf(v - bf2f(hv));
    }
  }
}

// ============ 5. fused: WO GEMM + residual (+ w2-transpose co-blocks) =======
__global__ __launch_bounds__(256, 4) void k_gemm_wo(
    const ushort* __restrict__ oh, const ushort* __restrict__ ol,
    const ushort* __restrict__ woh, const ushort* __restrict__ wol,
    const float* __restrict__ x, float* __restrict__ hb,
    const float* __restrict__ w2, ushort* __restrict__ w2t)
{
  __shared__ __align__(16) char lds[32768];
  int bid = blockIdx.x, tid = threadIdx.x;

  if (bid >= 512) {                   // ---- tw2 co-blocks ----
    ushort* lt = (ushort*)lds;        // 64*72*2 = 9216 B
    int pid = bid - 512;
    for (int tt = pid; tt < 16*44*8; tt += 512) {
      int dt = tt & 15, rest = tt >> 4;
      int ft = rest % 44, e = rest / 44;
#pragma unroll
      for (int i = 0; i < 4; i++) {
        int c = tid + i*256;
        int r = c >> 4, q = c & 15;
        float4 v = *(const float4*)(w2 + ((size_t)e*FF + ft*64 + r) * DM + dt*64 + q*4);
        lt[(q*4+0)*72 + r] = f2bf(v.x);
        lt[(q*4+1)*72 + r] = f2bf(v.y);
        lt[(q*4+2)*72 + r] = f2bf(v.z);
        lt[(q*4+3)*72 + r] = f2bf(v.w);
      }
      __syncthreads();
#pragma unroll
      for (int i = 0; i < 2; i++) {
        int c = tid + i*256;
        int d = c >> 3, fq = c & 7;
        *(uint4*)(w2t + ((size_t)e*DM + dt*64 + d) * FF + ft*64 + fq*8) =
            *(const uint4*)&lt[d*72 + fq*8];
      }
      __syncthreads();
    }
    return;
  }

  char* Ah = lds;          char* Al = lds + 8192;
  char* Bh = lds + 16384;  char* Bl = lds + 24576;
  int bnn = bid & 15, bm = bid >> 4;
  int lane = tid & 63, w = tid >> 6;
  int r0 = lane >> 3, pp = lane & 7;
  size_t asrc[2], bsrc[2]; int cdst[2];
#pragma unroll
  for (int i = 0; i < 2; i++) {
    int c = w * 2 + i;
    int row = c * 8 + r0;
    asrc[i] = (size_t)(bm * 64 + row) * DM + (pp ^ r0) * 8;
    bsrc[i] = (size_t)(bnn * 64 + row) * DM + (pp ^ r0) * 8;
    cdst[i] = c * 1024;
  }
  f32x4 acc[4] = {};
  for (int kb = 0; kb < DM; kb += 64) {
    __syncthreads();
#pragma unroll
    for (int i = 0; i < 2; i++) {
      gload16(oh + asrc[i] + kb, Ah + cdst[i]);
      gload16(ol + asrc[i] + kb, Al + cdst[i]);
      gload16(woh + bsrc[i] + kb, Bh + cdst[i]);
      gload16(wol + bsrc[i] + kb, Bl + cdst[i]);
    }
    __syncthreads();
#pragma unroll
    for (int kk = 0; kk < 2; kk++) {
      int j = kk * 4 + (lane >> 4);
      int row = w * 16 + (lane & 15);
      short8 ar = *(const short8*)(Ah + LDSWZB(row, j));
      short8 al = *(const short8*)(Al + LDSWZB(row, j));
#pragma unroll
      for (int ni = 0; ni < 4; ni++) {
        int n = ni * 16 + (lane & 15);
        short8 b_h = *(const short8*)(Bh + LDSWZB(n, j));
        short8 b_l = *(const short8*)(Bl + LDSWZB(n, j));
        acc[ni] = MFMA(ar, b_h, acc[ni]);
        acc[ni] = MFMA(al, b_h, acc[ni]);
        acc[ni] = MFMA(ar, b_l, acc[ni]);
      }
    }
  }
#pragma unroll
  for (int ni = 0; ni < 4; ni++)
#pragma unroll
    for (int r = 0; r < 4; r++) {
      int rg = bm*64 + w*16 + (lane >> 4)*4 + r;
      int cg = bnn*64 + ni*16 + (lane & 15);
      hb[(size_t)rg * DM + cg] = x[(size_t)rg * DM + cg] + acc[ni][r];
    }
}

// ============ 6. FFN RMSNorm + fp32 gate + top-2 (records rank in pos) ======
__global__ __launch_bounds__(256) void k_gate(
    const float* __restrict__ hb, const float* __restrict__ fw, const float* __restrict__ gwt,
    ushort* __restrict__ tb, int* __restrict__ idx, float* __restrict__ ew,
    int* __restrict__ cnt, int* __restrict__ pos)
{
  int t = blockIdx.x, tid = threadIdx.x;
  float4 v = ((const float4*)(hb + (size_t)t * DM))[tid];
  float ss = v.x*v.x + v.y*v.y + v.z*v.z + v.w*v.w;
#pragma unroll
  for (int m = 32; m >= 1; m >>= 1) ss += __shfl_xor(ss, m);
  __shared__ float sh[4];
  if ((tid & 63) == 0) sh[tid >> 6] = ss;
  __syncthreads();
  ss = sh[0] + sh[1] + sh[2] + sh[3];
  float rstd = 1.0f / sqrtf(ss * (1.0f / DM) + 1e-5f);
  float4 wv = ((const float4*)fw)[tid];
  float tv0 = v.x*rstd*wv.x, tv1 = v.y*rstd*wv.y, tv2 = v.z*rstd*wv.z, tv3 = v.w*rstd*wv.w;
  ((uint2*)(tb + (size_t)t * DM))[tid] = mku2(pk2(tv0, tv1), pk2(tv2, tv3));
  float ge[8];
#pragma unroll
  for (int e = 0; e < 8; e++) {
    float4 gv = ((const float4*)(gwt + (size_t)e * DM))[tid];
    float s = tv0*gv.x + tv1*gv.y + tv2*gv.z + tv3*gv.w;
#pragma unroll
    for (int m = 32; m >= 1; m >>= 1) s += __shfl_xor(s, m);
    ge[e] = s;
  }
  __shared__ float gsh[4][8];
  if ((tid & 63) == 0) {
#pragma unroll
    for (int e = 0; e < 8; e++) gsh[tid >> 6][e] = ge[e];
  }
  __syncthreads();
  if (tid == 0) {
    float lg[8];
#pragma unroll
    for (int e = 0; e < 8; e++) lg[e] = gsh[0][e] + gsh[1][e] + gsh[2][e] + gsh[3][e];
    int i0 = 0;
    for (int e = 1; e < 8; e++) if (lg[e] > lg[i0]) i0 = e;
    int i1 = (i0 == 0) ? 1 : 0;
    for (int e = 0; e < 8; e++) if (e != i0 && lg[e] > lg[i1]) i1 = e;
    float ex = __expf(lg[i1] - lg[i0]);
    idx[2*t] = i0; idx[2*t+1] = i1;
    ew[2*t] = 1.0f / (1.0f + ex); ew[2*t+1] = ex / (1.0f + ex);
    pos[2*t]   = atomicAdd(&cnt[i0], 1);
    pos[2*t+1] = atomicAdd(&cnt[i1], 1);
  }
}

// ============ 7. merged offsets + scatter (1 block); 256-row tiles ============
__global__ __launch_bounds__(256) void k_offscatter(
    const int* __restrict__ cnt, int* __restrict__ off, int* __restrict__ tmap,
    const int* __restrict__ idx, int* __restrict__ ent, int* __restrict__ pos)
{
  __shared__ int soff[8];
  int tid = threadIdx.x;
  if (tid == 0) {
    int a = 0, nt = 0;
    for (int e = 0; e < 8; e++) {
      off[e] = a; soff[e] = a; a += cnt[e];
      int m = (cnt[e] + 255) >> 8;
      for (int j = 0; j < m; j++) { tmap[1 + nt] = (e << 8) | j; nt++; }
    }
    tmap[0] = nt;
  }
  __syncthreads();
  for (int s = tid; s < 2*TT; s += 256) {
    int e = idx[s];
    int g = soff[e] + pos[s];
    ent[g] = s;
    pos[s] = g;
  }
}

// ============ 10. grouped expert GEMM x1/x3 ============
// 512 threads (8 waves: 4 row x 2 col), BM=256, BN=64(x2), BK=64, all-bf16,
// single-buffer 48KB (A 32K | B1 8K | B3 8K), 3 blocks/CU.
// BM=256 halves per-expert weight re-reads vs r8's BM=128.
// grid (44 nt, 24 tiles[256-row]).
__global__ __launch_bounds__(512, 3) void k_moe13(
    const ushort* __restrict__ tb, const ushort* __restrict__ w1b, const ushort* __restrict__ w3b,
    const int* __restrict__ ent, const float* __restrict__ ew,
    const int* __restrict__ cnt, const int* __restrict__ off, const int* __restrict__ tmap,
    ushort* __restrict__ gb)
{
  int y = blockIdx.y;
  if (y >= tmap[0]) return;
  int tm = tmap[1 + y];
  int e = tm >> 8, mt = tm & 255;
  int nt = blockIdx.x;
  int cn = cnt[e], oe = off[e];
  __shared__ __align__(16) char lds[49152];   // A 32K | B1 8K | B3 8K
  char* Ab = lds;
  char* B1 = lds + 32768;
  char* B3 = lds + 40960;
  int tid = threadIdx.x, lane = tid & 63, w = tid >> 6;
  int wr = w >> 1, wc = w & 1;
  int r0 = lane >> 3, pp = lane & 7;

  // A: 32 chunks (8 rows x 8 slots each); wave w stages chunks w*4..w*4+3
  const ushort* abase = tb + (pp ^ r0) * 8;
  unsigned aoff[4];
#pragma unroll
  for (int i = 0; i < 4; i++) {
    int c = w * 4 + i;
    int r = c * 8 + r0;
    int g = oe + mt * 256 + r; if (g > 2*TT - 1) g = 2*TT - 1;
    aoff[i] = (unsigned)((ent[g] >> 1) * DM);
  }
  // B1/B3: 8 chunks each; wave w stages chunk w of both
  size_t bofs = ((size_t)e * FF + nt * 64 + w * 8 + r0) * DM + (pp ^ r0) * 8;

  f32x4 acc1[4][2] = {}, acc3[4][2] = {};

  for (int kb = 0; kb < DM; kb += 64) {
    __syncthreads();
#pragma unroll
    for (int i = 0; i < 4; i++)
      gload16(abase + aoff[i] + kb, Ab + (w * 4 + i) * 1024);
    gload16(w1b + bofs + kb, B1 + w * 1024);
    gload16(w3b + bofs + kb, B3 + w * 1024);
    __syncthreads();
#pragma unroll
    for (int kk = 0; kk < 2; kk++) {
      int j = kk * 4 + (lane >> 4);
      short8 af[4];
#pragma unroll
      for (int mi = 0; mi < 4; mi++) {
        int row = wr * 64 + mi * 16 + (lane & 15);
        af[mi] = *(const short8*)(Ab + LDSWZB(row, j));
      }
#pragma unroll
      for (int ni = 0; ni < 2; ni++) {
        int n = wc * 32 + ni * 16 + (lane & 15);
        short8 b1f = *(const short8*)(B1 + LDSWZB(n, j));
        short8 b3f = *(const short8*)(B3 + LDSWZB(n, j));
#pragma unroll
        for (int mi = 0; mi < 4; mi++) {
          acc1[mi][ni] = MFMA(af[mi], b1f, acc1[mi][ni]);
          acc3[mi][ni] = MFMA(af[mi], b3f, acc3[mi][ni]);
        }
      }
    }
  }
#pragma unroll
  for (int mi = 0; mi < 4; mi++)
#pragma unroll
    for (int ni = 0; ni < 2; ni++)
#pragma unroll
      for (int r = 0; r < 4; r++) {
        int grow = mt * 256 + wr * 64 + mi * 16 + (lane >> 4) * 4 + r;
        if (grow < cn) {
          int g = oe + grow;
          float gwv = ew[ent[g]];
          int f = nt * 64 + wc * 32 + ni * 16 + (lane & 15);
          float x1 = acc1[mi][ni][r], x3 = acc3[mi][ni][r];
          float sg = x1 / (1.0f + __expf(-x1));
          gb[(size_t)g * FF + f] = f2bf(sg * x3 * gwv);
        }
      }
}

// ============ 11. grouped GEMM vs w2^T ============
// 512 threads (8 row-split waves), BM=256, BN=64, BK=64, 40KB, 4 blocks/CU.
// grid (16 nt, 24 tiles[256-row]).
__global__ __launch_bounds__(512, 4) void k_moe2(
    const ushort* __restrict__ gb, const ushort* __restrict__ w2t,
    const int* __restrict__ cnt, const int* __restrict__ off, const int* __restrict__ tmap,
    float* __restrict__ mr)
{
  int y = blockIdx.y;
  if (y >= tmap[0]) return;
  int tm = tmap[1 + y];
  int e = tm >> 8, mt = tm & 255;
  int nt = blockIdx.x;
  int cn = cnt[e], oe = off[e];
  __shared__ __align__(16) char lds[40960];  // A 32K | B 8K
  char* Ab = lds; char* Bb = lds + 32768;
  int tid = threadIdx.x, lane = tid & 63, w = tid >> 6;
  int r0 = lane >> 3, pp = lane & 7;

  const ushort* abase = gb + (pp ^ r0) * 8;
  unsigned aoff[4];
#pragma unroll
  for (int i = 0; i < 4; i++) {
    int c = w * 4 + i;
    int r = c * 8 + r0;
    int g = oe + mt * 256 + r; if (g > 2*TT - 1) g = 2*TT - 1;
    aoff[i] = (unsigned)(g * FF);
  }
  size_t bofs = ((size_t)e * DM + nt * 64 + w * 8 + r0) * FF + (pp ^ r0) * 8;

  f32x4 a2[2][4] = {};
  for (int kb = 0; kb < FF; kb += 64) {
    __syncthreads();
#pragma unroll
    for (int i = 0; i < 4; i++)
      gload16(abase + aoff[i] + kb, Ab + (w * 4 + i) * 1024);
    gload16(w2t + bofs + kb, Bb + w * 1024);
    __syncthreads();
#pragma unroll
    for (int kk = 0; kk < 2; kk++) {
      int j = kk * 4 + (lane >> 4);
      short8 af[2], bf[4];
#pragma unroll
      for (int mi = 0; mi < 2; mi++) {
        int row = w * 32 + mi * 16 + (lane & 15);
        af[mi] = *(const short8*)(Ab + LDSWZB(row, j));
      }
#pragma unroll
      for (int ni = 0; ni < 4; ni++) {
        int n = ni * 16 + (lane & 15);
        bf[ni] = *(const short8*)(Bb + LDSWZB(n, j));
      }
#pragma unroll
      for (int ni = 0; ni < 4; ni++)
#pragma unroll
        for (int mi = 0; mi < 2; mi++)
          a2[mi][ni] = MFMA(af[mi], bf[ni], a2[mi][ni]);
    }
  }
#pragma unroll
  for (int mi = 0; mi < 2; mi++)
#pragma unroll
    for (int ni = 0; ni < 4; ni++)
#pragma unroll
      for (int r = 0; r < 4; r++) {
        int grow = mt * 256 + w * 32 + mi * 16 + (lane >> 4) * 4 + r;
        if (grow < cn) {
          int cg = nt * 64 + ni * 16 + (lane & 15);
          mr[(size_t)(oe + grow) * DM + cg] = a2[mi][ni][r];
        }
      }
}

// ============ 12. final: out = h + moe(slot0) + moe(slot1) ============
__global__ __launch_bounds__(256) void k_final(
    const float* __restrict__ hb, const float* __restrict__ mr,
    const int* __restrict__ pos, float* __restrict__ out)
{
  int t = blockIdx.x, tid = threadIdx.x;
  int g0 = pos[2*t], g1 = pos[2*t+1];
  float4 a  = ((const float4*)(hb + (size_t)t * DM))[tid];
  float4 m0 = ((const float4*)(mr + (size_t)g0 * DM))[tid];
  float4 m1 = ((const float4*)(mr + (size_t)g1 * DM))[tid];
  float4 o;
  o.x = a.x + m0.x + m1.x; o.y = a.y + m0.y + m1.y;
  o.z = a.z + m0.z + m1.z; o.w = a.w + m0.w + m1.w;
  ((float4*)(out + (size_t)t * DM))[tid] = o;
}

// ======================= launcher =======================
extern "C" void kernel_launch(void* const* d_in, const int* in_sizes, int n_in,
                              void* d_out, int out_size, void* d_ws, size_t ws_size,
                              hipStream_t stream)
{
  const float* x   = (const float*)d_in[0];
  const float* fc  = (const float*)d_in[1];
  const float* fs  = (const float*)d_in[2];
  const float* anw = (const float*)d_in[3];
  const float* wq  = (const float*)d_in[4];
  const float* wk  = (const float*)d_in[5];
  const float* wv  = (const float*)d_in[6];
  const float* wo  = (const float*)d_in[7];
  const float* fnw = (const float*)d_in[8];
  const float* gwm = (const float*)d_in[9];
  const float* w1  = (const float*)d_in[10];
  const float* w2  = (const float*)d_in[11];
  const float* w3  = (const float*)d_in[12];
  float* out = (float*)d_out;

  char* p = (char*)d_ws;
  auto alloc = [&](size_t n) { char* r = p; p += (n + 255) & ~(size_t)255; return r; };
  ushort* xnh = (ushort*)alloc((size_t)TT*DM*2);
  ushort* xnl = (ushort*)alloc((size_t)TT*DM*2);
  char*   pad = alloc((size_t)8*1024*1024);   // fallback-alias headroom
  ushort* qh  = (ushort*)alloc((size_t)TT*DM*2);
  ushort* ql  = (ushort*)alloc((size_t)TT*DM*2);
  ushort* kh  = (ushort*)alloc((size_t)TT*DM*2);
  ushort* kl  = (ushort*)alloc((size_t)TT*DM*2);
  ushort* vh  = (ushort*)alloc((size_t)TT*DM*2);
  ushort* vl  = (ushort*)alloc((size_t)TT*DM*2);
  ushort* oh  = (ushort*)alloc((size_t)TT*DM*2);
  ushort* ol  = (ushort*)alloc((size_t)TT*DM*2);
  float*  hb  = (float*) alloc((size_t)TT*DM*4);
  ushort* tb  = (ushort*)alloc((size_t)TT*DM*2);
  ushort* w2t = (ushort*)alloc((size_t)NE*FF*DM*2);
  ushort* gb  = (ushort*)alloc((size_t)2*TT*FF*2);
  float*  mr  = (float*) alloc((size_t)2*TT*DM*4);
  int*    idx = (int*)   alloc((size_t)2*TT*4);
  float*  ew  = (float*) alloc((size_t)2*TT*4);
  int*    ent = (int*)   alloc((size_t)2*TT*4);
  int*    pos = (int*)   alloc((size_t)2*TT*4);
  int*    cnt = (int*)   alloc(32);
  int*    off = (int*)   alloc(32);
  int*    tmap= (int*)   alloc(256);
  (void)pad;

  // split attn weights live in mr's region (dead until k_moe2)
  ushort* wsp = (ushort*)mr;
  const size_t WN = (size_t)DM * DM;
  ushort* wqh = wsp;        ushort* wql = wsp + WN;
  ushort* wkh = wsp + 2*WN; ushort* wkl = wsp + 3*WN;
  ushort* wvh = wsp + 4*WN; ushort* wvl = wsp + 5*WN;
  ushort* woh = wsp + 6*WN; ushort* wol = wsp + 7*WN;

  // w3b always fresh tail; w1b fresh if ws allows (enables attn-fused cw13),
  // else aliases the dead-at-moe13 front region (fallback path).
  ushort* w3b = (ushort*)alloc((size_t)NE*FF*DM*2);
  ushort* w1b_fresh = (ushort*)alloc((size_t)NE*FF*DM*2);
  bool big = ((size_t)(p - (char*)d_ws) <= ws_size);
  ushort* w1b = big ? w1b_fresh : (ushort*)d_ws;

  hipMemsetAsync(cnt, 0, 32, stream);
  k_pre<<<6144, 256, 0, stream>>>(x, anw, xnh, xnl, wq, wk, wv, wo,
      wqh, wql, wkh, wkl, wvh, wvl, woh, wol);
  k_gemm_qkv<<<384, 256, 0, stream>>>(xnh, xnl,
      wqh, wql, wkh, wkl, wvh, wvl, fc, fs, qh, ql, kh, kl, vh, vl);
  if (big) {
    k_attn_prep<<<1024, 256, 0, stream>>>(qh, ql, kh, kl, vh, vl, oh, ol,
        w1, w3, w1b, w3b);
  } else {
    k_attn_prep<<<512, 256, 0, stream>>>(qh, ql, kh, kl, vh, vl, oh, ol,
        w1, w3, w1b, w3b);
  }
  k_gemm_wo<<<1024, 256, 0, stream>>>(oh, ol, woh, wol, x, hb, w2, w2t);
  k_gate<<<TT, 256, 0, stream>>>(hb, fnw, gwm, tb, idx, ew, cnt, pos);
  k_offscatter<<<1, 256, 0, stream>>>(cnt, off, tmap, idx, ent, pos);
  if (!big) {
    k_cw13<<<dim3(2048, 2), 256, 0, stream>>>(w1, w3, w1b, w3b);
  }
  k_moe13<<<dim3(44, 24), 512, 0, stream>>>(tb, w1b, w3b, ent, ew, cnt, off, tmap, gb);
  k_moe2<<<dim3(16, 24), 512, 0, stream>>>(gb, w2t, cnt, off, tmap, mr);
  k_final<<<TT, 256, 0, stream>>>(hb, mr, pos, out);
  (void)in_sizes; (void)n_in; (void)out_size;
}

// Round 17
// 387.867 us; speedup vs baseline: 1.1258x; 1.1258x over previous
//
#include <hip/hip_runtime.h>

#define DI __device__ __forceinline__

typedef __attribute__((ext_vector_type(8))) short short8;
typedef __attribute__((ext_vector_type(4))) float f32x4;

// ---- problem constants ----
#define DM   1024      // model dim
#define TT   2048      // total tokens (B*S)
#define SEQ  1024
#define NHD  16        // heads
#define HDD  64        // head dim
#define NE   8         // experts
#define FF   2816

DI ushort f2bf(float f){
  union { float f; unsigned u; } c; c.f = f;
  unsigned u = c.u;
  u += 0x7fffu + ((u >> 16) & 1u);
  return (ushort)(u >> 16);
}
DI float bf2f(ushort b){
  union { unsigned u; float f; } c; c.u = ((unsigned)b) << 16;
  return c.f;
}
DI unsigned pk2(float a, float b){ return (unsigned)f2bf(a) | ((unsigned)f2bf(b) << 16); }
DI uint2 mku2(unsigned a, unsigned b){ uint2 r; r.x = a; r.y = b; return r; }

DI f32x4 MFMA(short8 a, short8 b, f32x4 c){
  return __builtin_amdgcn_mfma_f32_16x16x32_bf16(a, b, c, 0, 0, 0);
}

// async global->LDS, 16B per lane; LDS dest is wave-uniform base + lane*16
DI void gload16(const void* g, void* l){
  __builtin_amdgcn_global_load_lds(
      (const __attribute__((address_space(1))) unsigned*)g,
      (__attribute__((address_space(3))) unsigned*)l, 16, 0, 0);
}

// swizzled LDS byte offset, rows of 128B, 8 chunks of 16B (proven zero-conflict)
#define LDSWZB(row, p) (((row) * 128) + ((((p) ^ ((row) & 7))) * 16))

// ============ 1. fused: RMSNorm(x) + attn-weight split ============
__global__ __launch_bounds__(256) void k_pre(
    const float* __restrict__ x, const float* __restrict__ anw,
    ushort* __restrict__ xh, ushort* __restrict__ xl,
    const float* __restrict__ wq, const float* __restrict__ wk,
    const float* __restrict__ wv, const float* __restrict__ wo,
    ushort* __restrict__ wqh, ushort* __restrict__ wql,
    ushort* __restrict__ wkh, ushort* __restrict__ wkl,
    ushort* __restrict__ wvh, ushort* __restrict__ wvl,
    ushort* __restrict__ woh, ushort* __restrict__ wol)
{
  int bid = blockIdx.x, tid = threadIdx.x;
  if (bid >= 2048) {                 // ---- wsplit ----
    int q = bid - 2048;
    int y = q >> 10;
    const float* W = y == 0 ? wq : (y == 1 ? wk : (y == 2 ? wv : wo));
    ushort* H = y == 0 ? wqh : (y == 1 ? wkh : (y == 2 ? wvh : woh));
    ushort* L = y == 0 ? wql : (y == 1 ? wkl : (y == 2 ? wvl : wol));
    int i = (q & 1023) * 256 + tid;
    float4 v = ((const float4*)W)[i];
    ushort h0 = f2bf(v.x), h1 = f2bf(v.y), h2 = f2bf(v.z), h3 = f2bf(v.w);
    ((uint2*)H)[i] = mku2((unsigned)h0 | ((unsigned)h1 << 16),
                          (unsigned)h2 | ((unsigned)h3 << 16));
    ((uint2*)L)[i] = mku2(pk2(v.x - bf2f(h0), v.y - bf2f(h1)),
                          pk2(v.z - bf2f(h2), v.w - bf2f(h3)));
    return;
  }
  // ---- rmsnorm ----
  int row = bid;
  float4 v = ((const float4*)(x + (size_t)row * DM))[tid];
  float ss = v.x*v.x + v.y*v.y + v.z*v.z + v.w*v.w;
#pragma unroll
  for (int m = 32; m >= 1; m >>= 1) ss += __shfl_xor(ss, m);
  __shared__ float sh[4];
  if ((tid & 63) == 0) sh[tid >> 6] = ss;
  __syncthreads();
  ss = sh[0] + sh[1] + sh[2] + sh[3];
  float rstd = 1.0f / sqrtf(ss * (1.0f / DM) + 1e-5f);
  float4 wv2 = ((const float4*)anw)[tid];
  float o0 = v.x * rstd * wv2.x, o1 = v.y * rstd * wv2.y;
  float o2 = v.z * rstd * wv2.z, o3 = v.w * rstd * wv2.w;
  ushort h0 = f2bf(o0), h1 = f2bf(o1), h2 = f2bf(o2), h3 = f2bf(o3);
  ((uint2*)(xh + (size_t)row * DM))[tid] =
      mku2((unsigned)h0 | ((unsigned)h1 << 16), (unsigned)h2 | ((unsigned)h3 << 16));
  ((uint2*)(xl + (size_t)row * DM))[tid] =
      mku2(pk2(o0 - bf2f(h0), o1 - bf2f(h1)), pk2(o2 - bf2f(h2), o3 - bf2f(h3)));
}

// ============ 1c. standalone cw13 (fallback) ============
__global__ __launch_bounds__(256) void k_cw13(const float* __restrict__ w1,
                                              const float* __restrict__ w3,
                                              ushort* __restrict__ w1b,
                                              ushort* __restrict__ w3b)
{
  const float* src = blockIdx.y ? w3 : w1;
  ushort* dst = blockIdx.y ? w3b : w1b;
  const size_t N4 = (size_t)NE * FF * DM / 4;
  for (size_t i = (size_t)blockIdx.x * 256 + threadIdx.x; i < N4;
       i += (size_t)gridDim.x * 256) {
    float4 v = ((const float4*)src)[i];
    ((uint2*)dst)[i] = mku2(pk2(v.x, v.y), pk2(v.z, v.w));
  }
}

// ============ 2. fused QKV GEMM + RoPE (pure, r13 geometry) ============
// BM=128, BN=128, BK=64, 4 waves (2x2), 64KB LDS, grid 384.
__global__ __launch_bounds__(256, 2) void k_gemm_qkv(
    const ushort* __restrict__ xh, const ushort* __restrict__ xl,
    const ushort* __restrict__ wqh, const ushort* __restrict__ wql,
    const ushort* __restrict__ wkh, const ushort* __restrict__ wkl,
    const ushort* __restrict__ wvh, const ushort* __restrict__ wvl,
    const float* __restrict__ fc, const float* __restrict__ fs,
    ushort* __restrict__ qh, ushort* __restrict__ ql,
    ushort* __restrict__ kh, ushort* __restrict__ kl,
    ushort* __restrict__ vh, ushort* __restrict__ vl)
{
  __shared__ __align__(16) char lds[65536];
  char* Ah = lds;          char* Al = lds + 16384;
  char* Bh = lds + 32768;  char* Bl = lds + 49152;
  int bid = blockIdx.x, tid = threadIdx.x;
  int bn = bid % 24, bm = bid / 24;
  int which = bn >> 3, bnn = bn & 7;
  const ushort* WH = which == 0 ? wqh : (which == 1 ? wkh : wvh);
  const ushort* WL = which == 0 ? wql : (which == 1 ? wkl : wvl);
  int lane = tid & 63, w = tid >> 6, wr = w >> 1, wc = w & 1;
  int r0 = lane >> 3, pp = lane & 7;
  size_t asrc[4], bsrc[4]; int cdst[4];
#pragma unroll
  for (int i = 0; i < 4; i++) {
    int c = w * 4 + i;
    int row = c * 8 + r0;
    asrc[i] = (size_t)(bm * 128 + row) * DM + (pp ^ r0) * 8;
    bsrc[i] = (size_t)(bnn * 128 + row) * DM + (pp ^ r0) * 8;
    cdst[i] = c * 1024;
  }
  f32x4 acc[4][4] = {};
  for (int kb = 0; kb < DM; kb += 64) {
    __syncthreads();
#pragma unroll
    for (int i = 0; i < 4; i++) {
      gload16(xh + asrc[i] + kb, Ah + cdst[i]);
      gload16(xl + asrc[i] + kb, Al + cdst[i]);
      gload16(WH + bsrc[i] + kb, Bh + cdst[i]);
      gload16(WL + bsrc[i] + kb, Bl + cdst[i]);
    }
    __syncthreads();
#pragma unroll
    for (int kk = 0; kk < 2; kk++) {
      int j = kk * 4 + (lane >> 4);
      short8 ar[4], al[4];
#pragma unroll
      for (int mi = 0; mi < 4; mi++) {
        int row = wr * 64 + mi * 16 + (lane & 15);
        ar[mi] = *(const short8*)(Ah + LDSWZB(row, j));
        al[mi] = *(const short8*)(Al + LDSWZB(row, j));
      }
#pragma unroll
      for (int ni = 0; ni < 4; ni++) {
        int n = wc * 64 + ni * 16 + (lane & 15);
        short8 b_h = *(const short8*)(Bh + LDSWZB(n, j));
        short8 b_l = *(const short8*)(Bl + LDSWZB(n, j));
#pragma unroll
        for (int mi = 0; mi < 4; mi++) {
          acc[mi][ni] = MFMA(ar[mi], b_h, acc[mi][ni]);
          acc[mi][ni] = MFMA(al[mi], b_h, acc[mi][ni]);
          acc[mi][ni] = MFMA(ar[mi], b_l, acc[mi][ni]);
        }
      }
    }
  }
  ushort* OH = which == 0 ? qh : kh;
  ushort* OL = which == 0 ? ql : kl;
#pragma unroll
  for (int mi = 0; mi < 4; mi++)
#pragma unroll
    for (int ni = 0; ni < 4; ni++)
#pragma unroll
      for (int r = 0; r < 4; r++) {
        int rg = bm*128 + wr*64 + mi*16 + (lane >> 4)*4 + r;
        int cg = bnn*128 + wc*64 + ni*16 + (lane & 15);
        float v = acc[mi][ni][r];
        int b = rg >> 10, s = rg & 1023, hh = cg >> 6, hd = cg & 63;
        if (which <= 1) {
          float p = __shfl_xor(v, 1);
          int pi = hd >> 1;
          float c = fc[s*32 + pi], sn = fs[s*32 + pi];
          float rr = (hd & 1) ? (p * sn + v * c) : (v * c - p * sn);
          size_t o = ((size_t)(b*NHD + hh) * SEQ + s) * HDD + hd;
          ushort hv = f2bf(rr);
          OH[o] = hv; OL[o] = f2bf(rr - bf2f(hv));
        } else {
          size_t o = ((size_t)((b*NHD + hh)*HDD + hd)) * SEQ + s;
          ushort hv = f2bf(v);
          vh[o] = hv; vl[o] = f2bf(v - bf2f(hv));
        }
      }
}

// ============ 4. fused: causal flash attention + cw13 co-blocks ============
__global__ __launch_bounds__(256) void k_attn_prep(
    const ushort* __restrict__ qh_, const ushort* __restrict__ ql_,
    const ushort* __restrict__ kh_, const ushort* __restrict__ kl_,
    const ushort* __restrict__ vh_, const ushort* __restrict__ vl_,
    ushort* __restrict__ oh_, ushort* __restrict__ ol_,
    const float* __restrict__ w1, const float* __restrict__ w3,
    ushort* __restrict__ w1b, ushort* __restrict__ w3b)
{
  __shared__ __align__(16) char smem[49152];
  int bid = blockIdx.x, tid = threadIdx.x;

  if (bid >= 512) {                     // ---- cw13 co-blocks ----
    int pid = bid - 512;
    const size_t N4 = (size_t)NE * FF * DM / 4;
    for (size_t i = (size_t)pid * 256 + tid; i < N4; i += (size_t)512 * 256) {
      float4 v = ((const float4*)w1)[i];
      ((uint2*)w1b)[i] = mku2(pk2(v.x, v.y), pk2(v.z, v.w));
      float4 u = ((const float4*)w3)[i];
      ((uint2*)w3b)[i] = mku2(pk2(u.x, u.y), pk2(u.z, u.w));
    }
    return;
  }

  char* Kh = smem;          char* Kl = smem + 8192;
  char* Vh = smem + 16384;  char* Vl = smem + 24576;
  ushort* Ph = (ushort*)(smem + 32768);
  ushort* Pl = (ushort*)(smem + 40960);
  int qt = bid & 15, bh = bid >> 4;
  int lane = tid & 63, w = tid >> 6;
  int r0 = lane >> 3, pp = lane & 7;
  short8 qfh[2], qfl[2];
  int qrow = qt*64 + w*16 + (lane & 15);
#pragma unroll
  for (int ks = 0; ks < 2; ks++) {
    size_t g = ((size_t)bh * SEQ + qrow) * HDD + ks*32 + (lane >> 4)*8;
    qfh[ks] = *(const short8*)(qh_ + g);
    qfl[ks] = *(const short8*)(ql_ + g);
  }
  size_t kbase[2], vbase[2];
#pragma unroll
  for (int i = 0; i < 2; i++) {
    int c = 2*w + i;
    kbase[i] = ((size_t)bh * SEQ + c*8 + r0) * 64 + (pp ^ r0) * 8;
    vbase[i] = ((size_t)bh * 64 + c*8 + r0) * SEQ + (pp ^ r0) * 8;
  }
  f32x4 oacc[4] = {};
  float mrun[4], lrun[4];
#pragma unroll
  for (int r = 0; r < 4; r++) { mrun[r] = -1e30f; lrun[r] = 0.0f; }

  for (int kt = 0; kt <= qt; kt++) {
    __syncthreads();
#pragma unroll
    for (int i = 0; i < 2; i++) {
      int c = 2*w + i;
      size_t ko = kbase[i] + (size_t)kt * 64 * 64;
      size_t vo = vbase[i] + (size_t)kt * 64;
      gload16(kh_ + ko, Kh + c*1024);
      gload16(kl_ + ko, Kl + c*1024);
      gload16(vh_ + vo, Vh + c*1024);
      gload16(vl_ + vo, Vl + c*1024);
    }
    __syncthreads();
    f32x4 sa[4] = {};
#pragma unroll
    for (int j2 = 0; j2 < 4; j2++) {
#pragma unroll
      for (int ks = 0; ks < 2; ks++) {
        int kr = j2*16 + (lane & 15);
        int j = ks*4 + (lane >> 4);
        short8 b_h = *(const short8*)(Kh + LDSWZB(kr, j));
        short8 b_l = *(const short8*)(Kl + LDSWZB(kr, j));
        sa[j2] = MFMA(qfh[ks], b_h, sa[j2]);
        sa[j2] = MFMA(qfl[ks], b_h, sa[j2]);
        sa[j2] = MFMA(qfh[ks], b_l, sa[j2]);
      }
    }
    float sv[4][4];
#pragma unroll
    for (int j2 = 0; j2 < 4; j2++)
#pragma unroll
      for (int r = 0; r < 4; r++) {
        float xx = sa[j2][r] * 0.125f;
        if (kt == qt) {
          int kv = j2*16 + (lane & 15), qi = w*16 + (lane >> 4)*4 + r;
          if (kv > qi) xx = -1e30f;
        }
        sv[j2][r] = xx;
      }
#pragma unroll
    for (int r = 0; r < 4; r++) {
      float mx = fmaxf(fmaxf(sv[0][r], sv[1][r]), fmaxf(sv[2][r], sv[3][r]));
#pragma unroll
      for (int m = 8; m >= 1; m >>= 1) mx = fmaxf(mx, __shfl_xor(mx, m));
      float mn = fmaxf(mrun[r], mx);
      float alp = __expf(mrun[r] - mn);
      mrun[r] = mn;
      float rs = 0.0f;
#pragma unroll
      for (int j2 = 0; j2 < 4; j2++) { float pv = __expf(sv[j2][r] - mn); sv[j2][r] = pv; rs += pv; }
#pragma unroll
      for (int m = 8; m >= 1; m >>= 1) rs += __shfl_xor(rs, m);
      lrun[r] = lrun[r] * alp + rs;
#pragma unroll
      for (int hf = 0; hf < 4; hf++) oacc[hf][r] *= alp;
    }
#pragma unroll
    for (int j2 = 0; j2 < 4; j2++)
#pragma unroll
      for (int r = 0; r < 4; r++) {
        int row = (lane >> 4)*4 + r, col = j2*16 + (lane & 15);
        int d = w*1024 + row*64 + (((col >> 3) ^ (row & 7)) * 8) + (col & 7);
        ushort hv = f2bf(sv[j2][r]);
        Ph[d] = hv; Pl[d] = f2bf(sv[j2][r] - bf2f(hv));
      }
#pragma unroll
    for (int hf = 0; hf < 4; hf++) {
#pragma unroll
      for (int ks = 0; ks < 2; ks++) {
        int prow = lane & 15;
        int j = ks*4 + (lane >> 4);
        int pg = (j ^ (prow & 7)) * 8;
        short8 pfh = *(const short8*)&Ph[w*1024 + prow*64 + pg];
        short8 pfl = *(const short8*)&Pl[w*1024 + prow*64 + pg];
        int vrow = hf*16 + (lane & 15);
        short8 vfh = *(const short8*)(Vh + LDSWZB(vrow, j));
        short8 vfl = *(const short8*)(Vl + LDSWZB(vrow, j));
        oacc[hf] = MFMA(pfh, vfh, oacc[hf]);
        oacc[hf] = MFMA(pfl, vfh, oacc[hf]);
        oacc[hf] = MFMA(pfh, vfl, oacc[hf]);
      }
    }
  }
  int b = bh >> 4, h = bh & 15;
#pragma unroll
  for (int r = 0; r < 4; r++) {
    float li = 1.0f / lrun[r];
    int srow = qt*64 + w*16 + (lane >> 4)*4 + r;
#pragma unroll
    for (int hf = 0; hf < 4; hf++) {
      float v = oacc[hf][r] * li;
      size_t o = ((size_t)(b*SEQ + srow)) * DM + h*HDD + hf*16 + (lane & 15);
      ushort hv = f2bf(v);
      oh_[o] = hv; ol_[o] = f2bf(v - bf2f(hv));
    }
  }
}

// ============ 5. fused: WO GEMM + residual (+ w2-transpose co-blocks) =======
__global__ __launch_bounds__(256, 4) void k_gemm_wo(
    const ushort* __restrict__ oh, const ushort* __restrict__ ol,
    const ushort* __restrict__ woh, const ushort* __restrict__ wol,
    const float* __restrict__ x, float* __restrict__ hb,
    const float* __restrict__ w2, ushort* __restrict__ w2t)
{
  __shared__ __align__(16) char lds[32768];
  int bid = blockIdx.x, tid = threadIdx.x;

  if (bid >= 512) {                   // ---- tw2 co-blocks ----
    ushort* lt = (ushort*)lds;        // 64*72*2 = 9216 B
    int pid = bid - 512;
    for (int tt = pid; tt < 16*44*8; tt += 512) {
      int dt = tt & 15, rest = tt >> 4;
      int ft = rest % 44, e = rest / 44;
#pragma unroll
      for (int i = 0; i < 4; i++) {
        int c = tid + i*256;
        int r = c >> 4, q = c & 15;
        float4 v = *(const float4*)(w2 + ((size_t)e*FF + ft*64 + r) * DM + dt*64 + q*4);
        lt[(q*4+0)*72 + r] = f2bf(v.x);
        lt[(q*4+1)*72 + r] = f2bf(v.y);
        lt[(q*4+2)*72 + r] = f2bf(v.z);
        lt[(q*4+3)*72 + r] = f2bf(v.w);
      }
      __syncthreads();
#pragma unroll
      for (int i = 0; i < 2; i++) {
        int c = tid + i*256;
        int d = c >> 3, fq = c & 7;
        *(uint4*)(w2t + ((size_t)e*DM + dt*64 + d) * FF + ft*64 + fq*8) =
            *(const uint4*)&lt[d*72 + fq*8];
      }
      __syncthreads();
    }
    return;
  }

  char* Ah = lds;          char* Al = lds + 8192;
  char* Bh = lds + 16384;  char* Bl = lds + 24576;
  int bnn = bid & 15, bm = bid >> 4;
  int lane = tid & 63, w = tid >> 6;
  int r0 = lane >> 3, pp = lane & 7;
  size_t asrc[2], bsrc[2]; int cdst[2];
#pragma unroll
  for (int i = 0; i < 2; i++) {
    int c = w * 2 + i;
    int row = c * 8 + r0;
    asrc[i] = (size_t)(bm * 64 + row) * DM + (pp ^ r0) * 8;
    bsrc[i] = (size_t)(bnn * 64 + row) * DM + (pp ^ r0) * 8;
    cdst[i] = c * 1024;
  }
  f32x4 acc[4] = {};
  for (int kb = 0; kb < DM; kb += 64) {
    __syncthreads();
#pragma unroll
    for (int i = 0; i < 2; i++) {
      gload16(oh + asrc[i] + kb, Ah + cdst[i]);
      gload16(ol + asrc[i] + kb, Al + cdst[i]);
      gload16(woh + bsrc[i] + kb, Bh + cdst[i]);
      gload16(wol + bsrc[i] + kb, Bl + cdst[i]);
    }
    __syncthreads();
#pragma unroll
    for (int kk = 0; kk < 2; kk++) {
      int j = kk * 4 + (lane >> 4);
      int row = w * 16 + (lane & 15);
      short8 ar = *(const short8*)(Ah + LDSWZB(row, j));
      short8 al = *(const short8*)(Al + LDSWZB(row, j));
#pragma unroll
      for (int ni = 0; ni < 4; ni++) {
        int n = ni * 16 + (lane & 15);
        short8 b_h = *(const short8*)(Bh + LDSWZB(n, j));
        short8 b_l = *(const short8*)(Bl + LDSWZB(n, j));
        acc[ni] = MFMA(ar, b_h, acc[ni]);
        acc[ni] = MFMA(al, b_h, acc[ni]);
        acc[ni] = MFMA(ar, b_l, acc[ni]);
      }
    }
  }
#pragma unroll
  for (int ni = 0; ni < 4; ni++)
#pragma unroll
    for (int r = 0; r < 4; r++) {
      int rg = bm*64 + w*16 + (lane >> 4)*4 + r;
      int cg = bnn*64 + ni*16 + (lane & 15);
      hb[(size_t)rg * DM + cg] = x[(size_t)rg * DM + cg] + acc[ni][r];
    }
}

// ============ 6. FFN RMSNorm + fp32 gate + top-2 (records rank in pos) ======
__global__ __launch_bounds__(256) void k_gate(
    const float* __restrict__ hb, const float* __restrict__ fw, const float* __restrict__ gwt,
    ushort* __restrict__ tb, int* __restrict__ idx, float* __restrict__ ew,
    int* __restrict__ cnt, int* __restrict__ pos)
{
  int t = blockIdx.x, tid = threadIdx.x;
  float4 v = ((const float4*)(hb + (size_t)t * DM))[tid];
  float ss = v.x*v.x + v.y*v.y + v.z*v.z + v.w*v.w;
#pragma unroll
  for (int m = 32; m >= 1; m >>= 1) ss += __shfl_xor(ss, m);
  __shared__ float sh[4];
  if ((tid & 63) == 0) sh[tid >> 6] = ss;
  __syncthreads();
  ss = sh[0] + sh[1] + sh[2] + sh[3];
  float rstd = 1.0f / sqrtf(ss * (1.0f / DM) + 1e-5f);
  float4 wv = ((const float4*)fw)[tid];
  float tv0 = v.x*rstd*wv.x, tv1 = v.y*rstd*wv.y, tv2 = v.z*rstd*wv.z, tv3 = v.w*rstd*wv.w;
  ((uint2*)(tb + (size_t)t * DM))[tid] = mku2(pk2(tv0, tv1), pk2(tv2, tv3));
  float ge[8];
#pragma unroll
  for (int e = 0; e < 8; e++) {
    float4 gv = ((const float4*)(gwt + (size_t)e * DM))[tid];
    float s = tv0*gv.x + tv1*gv.y + tv2*gv.z + tv3*gv.w;
#pragma unroll
    for (int m = 32; m >= 1; m >>= 1) s += __shfl_xor(s, m);
    ge[e] = s;
  }
  __shared__ float gsh[4][8];
  if ((tid & 63) == 0) {
#pragma unroll
    for (int e = 0; e < 8; e++) gsh[tid >> 6][e] = ge[e];
  }
  __syncthreads();
  if (tid == 0) {
    float lg[8];
#pragma unroll
    for (int e = 0; e < 8; e++) lg[e] = gsh[0][e] + gsh[1][e] + gsh[2][e] + gsh[3][e];
    int i0 = 0;
    for (int e = 1; e < 8; e++) if (lg[e] > lg[i0]) i0 = e;
    int i1 = (i0 == 0) ? 1 : 0;
    for (int e = 0; e < 8; e++) if (e != i0 && lg[e] > lg[i1]) i1 = e;
    float ex = __expf(lg[i1] - lg[i0]);
    idx[2*t] = i0; idx[2*t+1] = i1;
    ew[2*t] = 1.0f / (1.0f + ex); ew[2*t+1] = ex / (1.0f + ex);
    pos[2*t]   = atomicAdd(&cnt[i0], 1);
    pos[2*t+1] = atomicAdd(&cnt[i1], 1);
  }
}

// ============ 7. merged offsets + scatter (1 block); 128-row tiles ============
__global__ __launch_bounds__(256) void k_offscatter(
    const int* __restrict__ cnt, int* __restrict__ off, int* __restrict__ tmap,
    const int* __restrict__ idx, int* __restrict__ ent, int* __restrict__ pos)
{
  __shared__ int soff[8];
  int tid = threadIdx.x;
  if (tid == 0) {
    int a = 0, nt = 0;
    for (int e = 0; e < 8; e++) {
      off[e] = a; soff[e] = a; a += cnt[e];
      int m = (cnt[e] + 127) >> 7;
      for (int j = 0; j < m; j++) { tmap[1 + nt] = (e << 8) | j; nt++; }
    }
    tmap[0] = nt;
  }
  __syncthreads();
  for (int s = tid; s < 2*TT; s += 256) {
    int e = idx[s];
    int g = soff[e] + pos[s];
    ent[g] = s;
    pos[s] = g;
  }
}

// ============ 10. grouped expert GEMM x1/x3 (r8-proven) ============
// 256 threads (4 waves 2x2), BM=128, BN=64(x2), BK=64, all-bf16,
// single-buffer 32KB, 2-barrier. grid (44 nt, 48 tiles[128-row]).
__global__ __launch_bounds__(256, 4) void k_moe13(
    const ushort* __restrict__ tb, const ushort* __restrict__ w1b, const ushort* __restrict__ w3b,
    const int* __restrict__ ent, const float* __restrict__ ew,
    const int* __restrict__ cnt, const int* __restrict__ off, const int* __restrict__ tmap,
    ushort* __restrict__ gb)
{
  int y = blockIdx.y;
  if (y >= tmap[0]) return;
  int tm = tmap[1 + y];
  int e = tm >> 8, mt = tm & 255;
  int nt = blockIdx.x;
  int cn = cnt[e], oe = off[e];
  __shared__ __align__(16) char lds[32768];
  char* Ab = lds;
  char* B1 = lds + 16384;
  char* B3 = lds + 24576;
  int tid = threadIdx.x, lane = tid & 63, w = tid >> 6;
  int wr = w >> 1, wc = w & 1;
  int r0 = lane >> 3, pp = lane & 7;

  const ushort* abase = tb + (pp ^ r0) * 8;
  unsigned aoff[4];
#pragma unroll
  for (int i = 0; i < 4; i++) {
    int c = w * 4 + i;
    int r = c * 8 + r0;
    int g = oe + mt * 128 + r; if (g > 2*TT - 1) g = 2*TT - 1;
    aoff[i] = (unsigned)((ent[g] >> 1) * DM);
  }
  size_t bofs[2];
#pragma unroll
  for (int i = 0; i < 2; i++) {
    int c = 2 * w + i;
    bofs[i] = ((size_t)e * FF + nt * 64 + c * 8 + r0) * DM + (pp ^ r0) * 8;
  }

  f32x4 acc1[4][2] = {}, acc3[4][2] = {};

  for (int kb = 0; kb < DM; kb += 64) {
    __syncthreads();
#pragma unroll
    for (int i = 0; i < 4; i++)
      gload16(abase + aoff[i] + kb, Ab + (w * 4 + i) * 1024);
#pragma unroll
    for (int i = 0; i < 2; i++) {
      gload16(w1b + bofs[i] + kb, B1 + (2 * w + i) * 1024);
      gload16(w3b + bofs[i] + kb, B3 + (2 * w + i) * 1024);
    }
    __syncthreads();
#pragma unroll
    for (int kk = 0; kk < 2; kk++) {
      int j = kk * 4 + (lane >> 4);
      short8 af[4];
#pragma unroll
      for (int mi = 0; mi < 4; mi++) {
        int row = wr * 64 + mi * 16 + (lane & 15);
        af[mi] = *(const short8*)(Ab + LDSWZB(row, j));
      }
#pragma unroll
      for (int ni = 0; ni < 2; ni++) {
        int n = wc * 32 + ni * 16 + (lane & 15);
        short8 b1f = *(const short8*)(B1 + LDSWZB(n, j));
        short8 b3f = *(const short8*)(B3 + LDSWZB(n, j));
#pragma unroll
        for (int mi = 0; mi < 4; mi++) {
          acc1[mi][ni] = MFMA(af[mi], b1f, acc1[mi][ni]);
          acc3[mi][ni] = MFMA(af[mi], b3f, acc3[mi][ni]);
        }
      }
    }
  }
#pragma unroll
  for (int mi = 0; mi < 4; mi++)
#pragma unroll
    for (int ni = 0; ni < 2; ni++)
#pragma unroll
      for (int r = 0; r < 4; r++) {
        int grow = mt * 128 + wr * 64 + mi * 16 + (lane >> 4) * 4 + r;
        if (grow < cn) {
          int g = oe + grow;
          float gwv = ew[ent[g]];
          int f = nt * 64 + wc * 32 + ni * 16 + (lane & 15);
          float x1 = acc1[mi][ni][r], x3 = acc3[mi][ni][r];
          float sg = x1 / (1.0f + __expf(-x1));
          gb[(size_t)g * FF + f] = f2bf(sg * x3 * gwv);
        }
      }
}

// ============ 11. grouped GEMM vs w2^T (r8-proven) ============
// BM=128, BN=64, BK=64, 4 waves, single-buffer 24KB. grid (16 nt, 48 tiles).
__global__ __launch_bounds__(256, 4) void k_moe2(
    const ushort* __restrict__ gb, const ushort* __restrict__ w2t,
    const int* __restrict__ cnt, const int* __restrict__ off, const int* __restrict__ tmap,
    float* __restrict__ mr)
{
  int y = blockIdx.y;
  if (y >= tmap[0]) return;
  int tm = tmap[1 + y];
  int e = tm >> 8, mt = tm & 255;
  int nt = blockIdx.x;
  int cn = cnt[e], oe = off[e];
  __shared__ __align__(16) char lds[24576];
  char* Ab = lds; char* Bb = lds + 16384;
  int tid = threadIdx.x, lane = tid & 63, w = tid >> 6;
  int r0 = lane >> 3, pp = lane & 7;

  const ushort* abase = gb + (pp ^ r0) * 8;
  unsigned aoff[4];
#pragma unroll
  for (int i = 0; i < 4; i++) {
    int c = w * 4 + i;
    int r = c * 8 + r0;
    int g = oe + mt * 128 + r; if (g > 2*TT - 1) g = 2*TT - 1;
    aoff[i] = (unsigned)(g * FF);
  }
  size_t bofs[2];
#pragma unroll
  for (int i = 0; i < 2; i++) {
    int c = 2 * w + i;
    bofs[i] = ((size_t)e * DM + nt * 64 + c * 8 + r0) * FF + (pp ^ r0) * 8;
  }

  f32x4 a2[2][4] = {};
  for (int kb = 0; kb < FF; kb += 64) {
    __syncthreads();
#pragma unroll
    for (int i = 0; i < 4; i++)
      gload16(abase + aoff[i] + kb, Ab + (w * 4 + i) * 1024);
#pragma unroll
    for (int i = 0; i < 2; i++)
      gload16(w2t + bofs[i] + kb, Bb + (2 * w + i) * 1024);
    __syncthreads();
#pragma unroll
    for (int kk = 0; kk < 2; kk++) {
      int j = kk * 4 + (lane >> 4);
      short8 af[2], bf[4];
#pragma unroll
      for (int mi = 0; mi < 2; mi++) {
        int row = w * 32 + mi * 16 + (lane & 15);
        af[mi] = *(const short8*)(Ab + LDSWZB(row, j));
      }
#pragma unroll
      for (int ni = 0; ni < 4; ni++) {
        int n = ni * 16 + (lane & 15);
        bf[ni] = *(const short8*)(Bb + LDSWZB(n, j));
      }
#pragma unroll
      for (int ni = 0; ni < 4; ni++)
#pragma unroll
        for (int mi = 0; mi < 2; mi++)
          a2[mi][ni] = MFMA(af[mi], bf[ni], a2[mi][ni]);
    }
  }
#pragma unroll
  for (int mi = 0; mi < 2; mi++)
#pragma unroll
    for (int ni = 0; ni < 4; ni++)
#pragma unroll
      for (int r = 0; r < 4; r++) {
        int grow = mt * 128 + w * 32 + mi * 16 + (lane >> 4) * 4 + r;
        if (grow < cn) {
          int cg = nt * 64 + ni * 16 + (lane & 15);
          mr[(size_t)(oe + grow) * DM + cg] = a2[mi][ni][r];
        }
      }
}

// ============ 12. final: out = h + moe(slot0) + moe(slot1) ============
__global__ __launch_bounds__(256) void k_final(
    const float* __restrict__ hb, const float* __restrict__ mr,
    const int* __restrict__ pos, float* __restrict__ out)
{
  int t = blockIdx.x, tid = threadIdx.x;
  int g0 = pos[2*t], g1 = pos[2*t+1];
  float4 a  = ((const float4*)(hb + (size_t)t * DM))[tid];
  float4 m0 = ((const float4*)(mr + (size_t)g0 * DM))[tid];
  float4 m1 = ((const float4*)(mr + (size_t)g1 * DM))[tid];
  float4 o;
  o.x = a.x + m0.x + m1.x; o.y = a.y + m0.y + m1.y;
  o.z = a.z + m0.z + m1.z; o.w = a.w + m0.w + m1.w;
  ((float4*)(out + (size_t)t * DM))[tid] = o;
}

// ======================= launcher =======================
extern "C" void kernel_launch(void* const* d_in, const int* in_sizes, int n_in,
                              void* d_out, int out_size, void* d_ws, size_t ws_size,
                              hipStream_t stream)
{
  const float* x   = (const float*)d_in[0];
  const float* fc  = (const float*)d_in[1];
  const float* fs  = (const float*)d_in[2];
  const float* anw = (const float*)d_in[3];
  const float* wq  = (const float*)d_in[4];
  const float* wk  = (const float*)d_in[5];
  const float* wv  = (const float*)d_in[6];
  const float* wo  = (const float*)d_in[7];
  const float* fnw = (const float*)d_in[8];
  const float* gwm = (const float*)d_in[9];
  const float* w1  = (const float*)d_in[10];
  const float* w2  = (const float*)d_in[11];
  const float* w3  = (const float*)d_in[12];
  float* out = (float*)d_out;

  char* p = (char*)d_ws;
  auto alloc = [&](size_t n) { char* r = p; p += (n + 255) & ~(size_t)255; return r; };
  ushort* xnh = (ushort*)alloc((size_t)TT*DM*2);
  ushort* xnl = (ushort*)alloc((size_t)TT*DM*2);
  char*   pad = alloc((size_t)8*1024*1024);   // fallback-alias headroom
  ushort* qh  = (ushort*)alloc((size_t)TT*DM*2);
  ushort* ql  = (ushort*)alloc((size_t)TT*DM*2);
  ushort* kh  = (ushort*)alloc((size_t)TT*DM*2);
  ushort* kl  = (ushort*)alloc((size_t)TT*DM*2);
  ushort* vh  = (ushort*)alloc((size_t)TT*DM*2);
  ushort* vl  = (ushort*)alloc((size_t)TT*DM*2);
  ushort* oh  = (ushort*)alloc((size_t)TT*DM*2);
  ushort* ol  = (ushort*)alloc((size_t)TT*DM*2);
  float*  hb  = (float*) alloc((size_t)TT*DM*4);
  ushort* tb  = (ushort*)alloc((size_t)TT*DM*2);
  ushort* w2t = (ushort*)alloc((size_t)NE*FF*DM*2);
  ushort* gb  = (ushort*)alloc((size_t)2*TT*FF*2);
  float*  mr  = (float*) alloc((size_t)2*TT*DM*4);
  int*    idx = (int*)   alloc((size_t)2*TT*4);
  float*  ew  = (float*) alloc((size_t)2*TT*4);
  int*    ent = (int*)   alloc((size_t)2*TT*4);
  int*    pos = (int*)   alloc((size_t)2*TT*4);
  int*    cnt = (int*)   alloc(32);
  int*    off = (int*)   alloc(32);
  int*    tmap= (int*)   alloc(256);
  (void)pad;

  // split attn weights live in mr's region (dead until k_moe2)
  ushort* wsp = (ushort*)mr;
  const size_t WN = (size_t)DM * DM;
  ushort* wqh = wsp;        ushort* wql = wsp + WN;
  ushort* wkh = wsp + 2*WN; ushort* wkl = wsp + 3*WN;
  ushort* wvh = wsp + 4*WN; ushort* wvl = wsp + 5*WN;
  ushort* woh = wsp + 6*WN; ushort* wol = wsp + 7*WN;

  // w3b always fresh tail; w1b fresh if ws allows (enables attn-fused cw13),
  // else aliases the dead-at-moe13 front region (fallback path).
  ushort* w3b = (ushort*)alloc((size_t)NE*FF*DM*2);
  ushort* w1b_fresh = (ushort*)alloc((size_t)NE*FF*DM*2);
  bool big = ((size_t)(p - (char*)d_ws) <= ws_size);
  ushort* w1b = big ? w1b_fresh : (ushort*)d_ws;

  hipMemsetAsync(cnt, 0, 32, stream);
  k_pre<<<6144, 256, 0, stream>>>(x, anw, xnh, xnl, wq, wk, wv, wo,
      wqh, wql, wkh, wkl, wvh, wvl, woh, wol);
  k_gemm_qkv<<<384, 256, 0, stream>>>(xnh, xnl,
      wqh, wql, wkh, wkl, wvh, wvl, fc, fs, qh, ql, kh, kl, vh, vl);
  if (big) {
    k_attn_prep<<<1024, 256, 0, stream>>>(qh, ql, kh, kl, vh, vl, oh, ol,
        w1, w3, w1b, w3b);
  } else {
    k_attn_prep<<<512, 256, 0, stream>>>(qh, ql, kh, kl, vh, vl, oh, ol,
        w1, w3, w1b, w3b);
  }
  k_gemm_wo<<<1024, 256, 0, stream>>>(oh, ol, woh, wol, x, hb, w2, w2t);
  k_gate<<<TT, 256, 0, stream>>>(hb, fnw, gwm, tb, idx, ew, cnt, pos);
  k_offscatter<<<1, 256, 0, stream>>>(cnt, off, tmap, idx, ent, pos);
  if (!big) {
    k_cw13<<<dim3(2048, 2), 256, 0, stream>>>(w1, w3, w1b, w3b);
  }
  k_moe13<<<dim3(44, 48), 256, 0, stream>>>(tb, w1b, w3b, ent, ew, cnt, off, tmap, gb);
  k_moe2<<<dim3(16, 48), 256, 0, stream>>>(gb, w2t, cnt, off, tmap, mr);
  k_final<<<TT, 256, 0, stream>>>(hb, mr, pos, out);
  (void)in_sizes; (void)n_in; (void)out_size;
}